// Round 9
// baseline (517.976 us; speedup 1.0000x reference)
//
#include <hip/hip_runtime.h>
#include <hip/hip_fp16.h>
#include <cstdint>

// ---------------------------------------------------------------------------
// 3-layer GAT (PyG GATConv semantics) on MI355X.
//   CSR by dst -> per layer: fp16 MFMA GEMM (fp32 acc, fused fp32 alpha
//   epilogue, SLICE-MAJOR fp16 feature out [NSL][N][32]) -> lane-parallel
//   edge weights [H][ET] -> XCD-sliced aggregate: slice = blockIdx%NSL binds
//   each 3.2MB channel-slice to one XCD's L2 (dispatch round-robin).
// Feature path fp16; logits/softmax/accumulation fp32.
// ---------------------------------------------------------------------------

typedef _Float16 f16;
typedef _Float16 f16x8 __attribute__((ext_vector_type(8)));
typedef float f32x4 __attribute__((ext_vector_type(4)));

__global__ __launch_bounds__(256) void count_kernel(const int* __restrict__ ei,
                                                    int E, int N,
                                                    int* __restrict__ deg) {
  int g = blockIdx.x * 256 + threadIdx.x;
  if (g >= E + N) return;
  int dst = (g < E) ? ei[E + g] : (g - E);
  atomicAdd(&deg[dst], 1);
}

__global__ __launch_bounds__(256) void deg_block_reduce(const int* __restrict__ deg,
                                                        int* __restrict__ bsum, int N) {
  __shared__ int red[4];
  int b = blockIdx.x;
  int v = 0;
#pragma unroll
  for (int s = 0; s < 4; ++s) {
    int idx = b * 1024 + s * 256 + threadIdx.x;
    if (idx < N) v += deg[idx];
  }
  for (int off = 32; off; off >>= 1) v += __shfl_down(v, off);
  if ((threadIdx.x & 63) == 0) red[threadIdx.x >> 6] = v;
  __syncthreads();
  if (threadIdx.x == 0) bsum[b] = red[0] + red[1] + red[2] + red[3];
}

__global__ __launch_bounds__(1024) void small_scan(const int* __restrict__ bsum,
                                                   int* __restrict__ bpre, int NB) {
  __shared__ int buf[1024];
  int v = (threadIdx.x < NB) ? bsum[threadIdx.x] : 0;
  buf[threadIdx.x] = v;
  __syncthreads();
  for (int off = 1; off < 1024; off <<= 1) {
    int tv = (threadIdx.x >= off) ? buf[threadIdx.x - off] : 0;
    __syncthreads();
    buf[threadIdx.x] += tv;
    __syncthreads();
  }
  if (threadIdx.x < NB) bpre[threadIdx.x] = buf[threadIdx.x] - v;
}

__global__ __launch_bounds__(1024) void scan_final(const int* __restrict__ deg,
                                                   const int* __restrict__ bpre,
                                                   int* __restrict__ row_off,
                                                   int* __restrict__ cursor,
                                                   int N, int total) {
  __shared__ int buf[1024];
  int b = blockIdx.x;
  int i = b * 1024 + threadIdx.x;
  int v = (i < N) ? deg[i] : 0;
  buf[threadIdx.x] = v;
  __syncthreads();
  for (int off = 1; off < 1024; off <<= 1) {
    int tv = (threadIdx.x >= off) ? buf[threadIdx.x - off] : 0;
    __syncthreads();
    buf[threadIdx.x] += tv;
    __syncthreads();
  }
  if (i < N) {
    int ro = bpre[b] + buf[threadIdx.x] - v;
    row_off[i] = ro;
    cursor[i] = ro;
  }
  if (i == 0) row_off[N] = total;
}

__global__ __launch_bounds__(256) void scatter_kernel(const int* __restrict__ ei,
                                                      int E, int N,
                                                      int* __restrict__ cursor,
                                                      int* __restrict__ esrc,
                                                      int* __restrict__ edst) {
  int g = blockIdx.x * 256 + threadIdx.x;
  if (g >= E + N) return;
  int src, dst;
  if (g < E) { src = ei[g]; dst = ei[E + g]; }
  else       { src = g - E; dst = src; }
  int pos = atomicAdd(&cursor[dst], 1);
  esrc[pos] = src;
  edst[pos] = dst;
}

__global__ __launch_bounds__(256) void convert_x(const float* __restrict__ x,
                                                 f16* __restrict__ xh, int n) {
  int i = (blockIdx.x * 256 + threadIdx.x) * 4;
  if (i >= n) return;
  float4 v = *reinterpret_cast<const float4*>(&x[i]);
  f16 o[4] = {(f16)v.x, (f16)v.y, (f16)v.z, (f16)v.w};
  *reinterpret_cast<uint2*>(&xh[i]) = *reinterpret_cast<uint2*>(o);
}

__global__ __launch_bounds__(256) void convert_wt(const float* __restrict__ W,
                                                  f16* __restrict__ Wt,
                                                  int K, int Ncol) {
  int t = blockIdx.x * 256 + threadIdx.x;
  if (t >= K * Ncol) return;
  int n = t % Ncol, k = t / Ncol;
  Wt[(size_t)n * K + k] = (f16)W[t];
}

// MFMA fp16 GEMM with fused fp32 alpha epilogue. Tout SLICE-MAJOR
// [Ncol/32][M][32]. ASL: A is slice-major [K/32][M][32] (layers 2-3).
template <int BN, bool ASL>
__global__ __launch_bounds__(256) void mfma_gemm_alpha(
    const f16* __restrict__ A, const f16* __restrict__ Bt,
    f16* __restrict__ Tout,
    const float* __restrict__ avec_src, const float* __restrict__ avec_dst,
    float* __restrict__ asrc, float* __restrict__ adst,
    int M, int K, int Ncol) {
  constexpr int CF = BN / 16;
  constexpr int HL = BN / 64;
  __shared__ f16 As[128][40];
  __shared__ f16 Bs[BN][40];
  int tid = threadIdx.x;
  int wv = tid >> 6, lane = tid & 63;
  int lrow = lane & 15, lkb = lane >> 4;
  int row0 = blockIdx.x * 128, col0 = blockIdx.y * BN;
  size_t Msl = (size_t)M * 32;

  f32x4 acc[2][CF];
#pragma unroll
  for (int rf = 0; rf < 2; ++rf)
#pragma unroll
    for (int cf = 0; cf < CF; ++cf) acc[rf][cf] = (f32x4){0.f, 0.f, 0.f, 0.f};

  for (int kk = 0; kk < K; kk += 32) {
#pragma unroll
    for (int q = 0; q < 2; ++q) {
      int slot = tid + q * 256;
      int r = slot >> 2, ko = (slot & 3) << 3;
      int gr = min(row0 + r, M - 1);
      const f16* Ap = ASL ? &A[(size_t)(kk >> 5) * Msl + (size_t)gr * 32 + ko]
                          : &A[(size_t)gr * K + kk + ko];
      *reinterpret_cast<f16x8*>(&As[r][ko]) = *reinterpret_cast<const f16x8*>(Ap);
    }
#pragma unroll
    for (int q = 0; q < BN / 64; ++q) {
      int slot = tid + q * 256;
      int c = slot >> 2, ko = (slot & 3) << 3;
      *reinterpret_cast<f16x8*>(&Bs[c][ko]) =
          *reinterpret_cast<const f16x8*>(&Bt[(size_t)(col0 + c) * K + kk + ko]);
    }
    __syncthreads();
    f16x8 af[2], bf[CF];
#pragma unroll
    for (int rf = 0; rf < 2; ++rf)
      af[rf] = *reinterpret_cast<f16x8*>(&As[wv * 32 + rf * 16 + lrow][lkb * 8]);
#pragma unroll
    for (int cf = 0; cf < CF; ++cf)
      bf[cf] = *reinterpret_cast<f16x8*>(&Bs[cf * 16 + lrow][lkb * 8]);
#pragma unroll
    for (int rf = 0; rf < 2; ++rf)
#pragma unroll
      for (int cf = 0; cf < CF; ++cf)
        acc[rf][cf] = __builtin_amdgcn_mfma_f32_16x16x32_f16(af[rf], bf[cf],
                                                             acc[rf][cf], 0, 0, 0);
    __syncthreads();
  }

  int Hh = Ncol >> 6;
  float avs[HL][4], avd[HL][4];
#pragma unroll
  for (int hl = 0; hl < HL; ++hl) {
    int hg = (col0 >> 6) + hl;
#pragma unroll
    for (int q = 0; q < 4; ++q) {
      avs[hl][q] = avec_src[hg * 64 + q * 16 + lrow];
      avd[hl][q] = avec_dst[hg * 64 + q * 16 + lrow];
    }
  }

#pragma unroll
  for (int rf = 0; rf < 2; ++rf) {
#pragma unroll
    for (int hl = 0; hl < HL; ++hl) {
      int hg = (col0 >> 6) + hl;
#pragma unroll
      for (int r = 0; r < 4; ++r) {
        float ps = 0.f, pd = 0.f;
#pragma unroll
        for (int q = 0; q < 4; ++q) {
          float v = acc[rf][hl * 4 + q][r];
          ps = fmaf(v, avs[hl][q], ps);
          pd = fmaf(v, avd[hl][q], pd);
        }
#pragma unroll
        for (int off = 1; off < 16; off <<= 1) {
          ps += __shfl_xor(ps, off);
          pd += __shfl_xor(pd, off);
        }
        int row = row0 + wv * 32 + rf * 16 + lkb * 4 + r;
        if (lrow == 0 && row < M) {
          asrc[row * Hh + hg] = ps;
          adst[row * Hh + hg] = pd;
        }
      }
    }
    // slice-major T store: col -> slice=col>>5, off=col&31
#pragma unroll
    for (int r = 0; r < 4; ++r) {
      int row = row0 + wv * 32 + rf * 16 + lkb * 4 + r;
      if (row < M) {
#pragma unroll
        for (int cf = 0; cf < CF; ++cf) {
          int col = col0 + cf * 16 + lrow;
          Tout[(size_t)(col >> 5) * Msl + (size_t)row * 32 + (col & 31)] =
              (f16)acc[rf][cf][r];
        }
      }
    }
  }
}

// Edge weights, layout [H][ET]: thread j computes all 4 heads (float4 logit
// loads), strided-coalesced stores. No max-shift (logits ~N(0,2), fp32-safe).
__global__ __launch_bounds__(256) void edge_weights_h4(
    const int* __restrict__ esrc, const int* __restrict__ edst,
    const float* __restrict__ asrc, const float* __restrict__ adst,
    float* __restrict__ w, int ET) {
  int j = blockIdx.x * 256 + threadIdx.x;
  if (j >= ET) return;
  float4 s4 = *reinterpret_cast<const float4*>(&asrc[esrc[j] * 4]);
  float4 d4 = *reinterpret_cast<const float4*>(&adst[edst[j] * 4]);
  float e0 = s4.x + d4.x; e0 = fmaxf(e0, 0.2f * e0);
  float e1 = s4.y + d4.y; e1 = fmaxf(e1, 0.2f * e1);
  float e2 = s4.z + d4.z; e2 = fmaxf(e2, 0.2f * e2);
  float e3 = s4.w + d4.w; e3 = fmaxf(e3, 0.2f * e3);
  w[j] = __expf(e0);
  w[ET + j] = __expf(e1);
  w[2 * ET + j] = __expf(e2);
  w[3 * ET + j] = __expf(e3);
}

__global__ __launch_bounds__(256) void edge_weights_h1(
    const int* __restrict__ esrc, const int* __restrict__ edst,
    const float* __restrict__ asrc, const float* __restrict__ adst,
    float* __restrict__ w, int ET) {
  int j = blockIdx.x * 256 + threadIdx.x;
  if (j >= ET) return;
  float e = asrc[esrc[j]] + adst[edst[j]];
  e = fmaxf(e, 0.2f * e);
  w[j] = __expf(e);
}

// XCD-sliced aggregate. slice = blockIdx % NSL (dispatch round-robins
// consecutive blocks across the 8 XCDs -> each XCD sees a fixed slice; the
// 3.2MB slice table stays L2-resident). Wave: 8 edge-groups x 8 lanes; lane
// owns 4 channels (8B load). 4 waves x 4 dsts per block.
template <int NSL, bool ELU, bool F32OUT>
__global__ __launch_bounds__(256) void aggregate_sliced(
    const f16* __restrict__ Tsl,   // [NSL][N][32]
    const int* __restrict__ row_off, const int* __restrict__ esrc,
    const float* __restrict__ w,   // [H][ET]
    const float* __restrict__ bias, void* __restrict__ outp,
    int N, int ET) {
  int s = blockIdx.x % NSL;
  int chunk = blockIdx.x / NSL;
  int wv = threadIdx.x >> 6, lane = threadIdx.x & 63;
  int g = lane >> 3, l = lane & 7;
  int head = s >> 1;  // 32-ch slice -> head = s*32/64 (0 when NSL==2)
  const f16* tb = Tsl + (size_t)s * N * 32;
  const float* wh = w + (size_t)head * ET;
  int dbase = chunk * 16 + wv * 4;
#pragma unroll
  for (int d = 0; d < 4; ++d) {
    int dst = dbase + d;
    if (dst >= N) return;
    int r0 = row_off[dst], r1 = row_off[dst + 1];
    float den = 0.f, ax = 0.f, ay = 0.f, az = 0.f, aw = 0.f;
    for (int j = r0 + g; j < r1; j += 8) {
      int sj = esrc[j];
      float wj = wh[j];
      den += wj;
      uint2 raw = *reinterpret_cast<const uint2*>(tb + (size_t)sj * 32 + l * 4);
      __half2 p0 = *reinterpret_cast<__half2*>(&raw.x);
      __half2 p1 = *reinterpret_cast<__half2*>(&raw.y);
      float2 f0 = __half22float2(p0);
      float2 f1 = __half22float2(p1);
      ax = fmaf(wj, f0.x, ax);
      ay = fmaf(wj, f0.y, ay);
      az = fmaf(wj, f1.x, az);
      aw = fmaf(wj, f1.y, aw);
    }
#pragma unroll
    for (int off = 8; off < 64; off <<= 1) {
      ax += __shfl_xor(ax, off);
      ay += __shfl_xor(ay, off);
      az += __shfl_xor(az, off);
      aw += __shfl_xor(aw, off);
      den += __shfl_xor(den, off);
    }
    if (lane < 8) {
      float rd = 1.f / den;
      int c0 = s * 32 + l * 4;
      float4 bv = *reinterpret_cast<const float4*>(&bias[c0]);
      float vx = ax * rd + bv.x, vy = ay * rd + bv.y;
      float vz = az * rd + bv.z, vw = aw * rd + bv.w;
      if (ELU) {
        vx = vx > 0.f ? vx : expm1f(vx);
        vy = vy > 0.f ? vy : expm1f(vy);
        vz = vz > 0.f ? vz : expm1f(vz);
        vw = vw > 0.f ? vw : expm1f(vw);
      }
      if (F32OUT) {
        *reinterpret_cast<float4*>((float*)outp + (size_t)dst * (NSL * 32) + c0) =
            make_float4(vx, vy, vz, vw);
      } else {
        f16 o[4] = {(f16)vx, (f16)vy, (f16)vz, (f16)vw};
        *reinterpret_cast<uint2*>((f16*)outp + ((size_t)s * N + dst) * 32 + l * 4) =
            *reinterpret_cast<uint2*>(o);
      }
    }
  }
}

extern "C" void kernel_launch(void* const* d_in, const int* in_sizes, int n_in,
                              void* d_out, int out_size, void* d_ws, size_t ws_size,
                              hipStream_t stream) {
  const float* x   = (const float*)d_in[0];
  const int*   ei  = (const int*)d_in[1];
  const float* W1  = (const float*)d_in[2];
  const float* as1 = (const float*)d_in[3];
  const float* ad1 = (const float*)d_in[4];
  const float* b1  = (const float*)d_in[5];
  const float* W2  = (const float*)d_in[6];
  const float* as2 = (const float*)d_in[7];
  const float* ad2 = (const float*)d_in[8];
  const float* b2  = (const float*)d_in[9];
  const float* W3  = (const float*)d_in[10];
  const float* as3 = (const float*)d_in[11];
  const float* ad3 = (const float*)d_in[12];
  const float* b3  = (const float*)d_in[13];
  float* out = (float*)d_out;

  const int Fin = 128, H = 4, C = 64, HC = H * C;  // 256
  const int N = in_sizes[0] / Fin;
  const int E = in_sizes[1] / 2;
  const int ET = E + N;
  const int NB = (N + 1023) / 1024;

  // workspace layout (~93 MB); T16/F16 slice-major [8][N][32], T16L3 [2][N][32]
  f16* xh    = (f16*)d_ws;                       // [N,128]
  f16* T16   = xh + (size_t)N * Fin;             // [8][N][32]
  f16* F16   = T16 + (size_t)N * HC;             // [8][N][32]
  f16* T16L3 = F16 + (size_t)N * HC;             // [2][N][32]
  f16* Wt1   = T16L3 + (size_t)N * C;            // [256,128]
  f16* Wt2   = Wt1 + HC * Fin;                   // [256,256]
  f16* Wt3   = Wt2 + HC * HC;                    // [64,256]
  float* asrc = (float*)(Wt3 + C * HC);          // [N,H]
  float* adst = asrc + (size_t)N * H;            // [N,H]
  float* wbuf = adst + (size_t)N * H;            // [4][ET]
  int* deg     = (int*)(wbuf + (size_t)ET * 4);
  int* row_off = deg + N;
  int* cursor  = row_off + (N + 1);
  int* bsum    = cursor + N;
  int* bpre    = bsum + NB;
  int* esrc    = bpre + NB;                      // [ET]
  int* edst    = esrc + ET;                      // [ET]

  // ---- CSR by destination ----
  hipMemsetAsync(deg, 0, N * sizeof(int), stream);
  count_kernel<<<(ET + 255) / 256, 256, 0, stream>>>(ei, E, N, deg);
  deg_block_reduce<<<NB, 256, 0, stream>>>(deg, bsum, N);
  small_scan<<<1, 1024, 0, stream>>>(bsum, bpre, NB);
  scan_final<<<NB, 1024, 0, stream>>>(deg, bpre, row_off, cursor, N, ET);
  scatter_kernel<<<(ET + 255) / 256, 256, 0, stream>>>(ei, E, N, cursor, esrc, edst);

  // ---- fp16 conversions ----
  convert_x<<<(N * Fin / 4 + 255) / 256, 256, 0, stream>>>(x, xh, N * Fin);
  convert_wt<<<(Fin * HC + 255) / 256, 256, 0, stream>>>(W1, Wt1, Fin, HC);
  convert_wt<<<(HC * HC + 255) / 256, 256, 0, stream>>>(W2, Wt2, HC, HC);
  convert_wt<<<(HC * C + 255) / 256, 256, 0, stream>>>(W3, Wt3, HC, C);

  int gx = (N + 127) / 128;
  int eb = (ET + 255) / 256;
  int agg4 = 8 * ((N + 15) / 16);
  int agg1 = 2 * ((N + 15) / 16);

  // ---- Layer 1: 128 -> 4x64 (concat) + ELU ----
  mfma_gemm_alpha<128, false><<<dim3(gx, 2), 256, 0, stream>>>(
      xh, Wt1, T16, as1, ad1, asrc, adst, N, Fin, HC);
  edge_weights_h4<<<eb, 256, 0, stream>>>(esrc, edst, asrc, adst, wbuf, ET);
  aggregate_sliced<8, true, false><<<agg4, 256, 0, stream>>>(
      T16, row_off, esrc, wbuf, b1, F16, N, ET);

  // ---- Layer 2: 256 -> 4x64 (concat) + ELU ----
  mfma_gemm_alpha<128, true><<<dim3(gx, 2), 256, 0, stream>>>(
      F16, Wt2, T16, as2, ad2, asrc, adst, N, HC, HC);
  edge_weights_h4<<<eb, 256, 0, stream>>>(esrc, edst, asrc, adst, wbuf, ET);
  aggregate_sliced<8, true, false><<<agg4, 256, 0, stream>>>(
      T16, row_off, esrc, wbuf, b2, F16, N, ET);

  // ---- Layer 3: 256 -> 1x64 ----
  mfma_gemm_alpha<64, true><<<dim3(gx, 1), 256, 0, stream>>>(
      F16, Wt3, T16L3, as3, ad3, asrc, adst, N, HC, C);
  edge_weights_h1<<<eb, 256, 0, stream>>>(esrc, edst, asrc, adst, wbuf, ET);
  aggregate_sliced<2, false, true><<<agg1, 256, 0, stream>>>(
      T16L3, row_off, esrc, wbuf, b3, out, N, ET);
}

// Round 10
// 337.247 us; speedup vs baseline: 1.5359x; 1.5359x over previous
//
#include <hip/hip_runtime.h>
#include <hip/hip_fp16.h>
#include <cstdint>

// ---------------------------------------------------------------------------
// 3-layer GAT (PyG GATConv semantics) on MI355X.
//   CSR by dst -> per layer: fp16 MFMA GEMM (fp32 acc) + fused fp32 alpha
//   epilogue -> lane-parallel edge weights -> wave-per-dst aggregate with
//   8-edge batched index prefetch (8 independent gathers in flight/wave).
// Feature path fp16; logits/softmax/accumulation fp32.
// ---------------------------------------------------------------------------

typedef _Float16 f16;
typedef _Float16 f16x8 __attribute__((ext_vector_type(8)));
typedef float f32x4 __attribute__((ext_vector_type(4)));

__global__ __launch_bounds__(256) void count_kernel(const int* __restrict__ ei,
                                                    int E, int N,
                                                    int* __restrict__ deg) {
  int g = blockIdx.x * 256 + threadIdx.x;
  if (g >= E + N) return;
  int dst = (g < E) ? ei[E + g] : (g - E);
  atomicAdd(&deg[dst], 1);
}

__global__ __launch_bounds__(256) void deg_block_reduce(const int* __restrict__ deg,
                                                        int* __restrict__ bsum, int N) {
  __shared__ int red[4];
  int b = blockIdx.x;
  int v = 0;
#pragma unroll
  for (int s = 0; s < 4; ++s) {
    int idx = b * 1024 + s * 256 + threadIdx.x;
    if (idx < N) v += deg[idx];
  }
  for (int off = 32; off; off >>= 1) v += __shfl_down(v, off);
  if ((threadIdx.x & 63) == 0) red[threadIdx.x >> 6] = v;
  __syncthreads();
  if (threadIdx.x == 0) bsum[b] = red[0] + red[1] + red[2] + red[3];
}

__global__ __launch_bounds__(1024) void small_scan(const int* __restrict__ bsum,
                                                   int* __restrict__ bpre, int NB) {
  __shared__ int buf[1024];
  int v = (threadIdx.x < NB) ? bsum[threadIdx.x] : 0;
  buf[threadIdx.x] = v;
  __syncthreads();
  for (int off = 1; off < 1024; off <<= 1) {
    int tv = (threadIdx.x >= off) ? buf[threadIdx.x - off] : 0;
    __syncthreads();
    buf[threadIdx.x] += tv;
    __syncthreads();
  }
  if (threadIdx.x < NB) bpre[threadIdx.x] = buf[threadIdx.x] - v;
}

__global__ __launch_bounds__(1024) void scan_final(const int* __restrict__ deg,
                                                   const int* __restrict__ bpre,
                                                   int* __restrict__ row_off,
                                                   int* __restrict__ cursor,
                                                   int N, int total) {
  __shared__ int buf[1024];
  int b = blockIdx.x;
  int i = b * 1024 + threadIdx.x;
  int v = (i < N) ? deg[i] : 0;
  buf[threadIdx.x] = v;
  __syncthreads();
  for (int off = 1; off < 1024; off <<= 1) {
    int tv = (threadIdx.x >= off) ? buf[threadIdx.x - off] : 0;
    __syncthreads();
    buf[threadIdx.x] += tv;
    __syncthreads();
  }
  if (i < N) {
    int ro = bpre[b] + buf[threadIdx.x] - v;
    row_off[i] = ro;
    cursor[i] = ro;
  }
  if (i == 0) row_off[N] = total;
}

__global__ __launch_bounds__(256) void scatter_kernel(const int* __restrict__ ei,
                                                      int E, int N,
                                                      int* __restrict__ cursor,
                                                      int* __restrict__ esrc,
                                                      int* __restrict__ edst) {
  int g = blockIdx.x * 256 + threadIdx.x;
  if (g >= E + N) return;
  int src, dst;
  if (g < E) { src = ei[g]; dst = ei[E + g]; }
  else       { src = g - E; dst = src; }
  int pos = atomicAdd(&cursor[dst], 1);
  esrc[pos] = src;
  edst[pos] = dst;
}

__global__ __launch_bounds__(256) void convert_x(const float* __restrict__ x,
                                                 f16* __restrict__ xh, int n) {
  int i = (blockIdx.x * 256 + threadIdx.x) * 4;
  if (i >= n) return;
  float4 v = *reinterpret_cast<const float4*>(&x[i]);
  f16 o[4] = {(f16)v.x, (f16)v.y, (f16)v.z, (f16)v.w};
  *reinterpret_cast<uint2*>(&xh[i]) = *reinterpret_cast<uint2*>(o);
}

__global__ __launch_bounds__(256) void convert_wt(const float* __restrict__ W,
                                                  f16* __restrict__ Wt,
                                                  int K, int Ncol) {
  int t = blockIdx.x * 256 + threadIdx.x;
  if (t >= K * Ncol) return;
  int n = t % Ncol, k = t / Ncol;
  Wt[(size_t)n * K + k] = (f16)W[t];
}

// MFMA fp16 GEMM  T = A@B  with fused fp32 alpha epilogue; T written fp16.
// Block: 256 thr (4 waves), tile 128 x BN, BK=32.
template <int BN>
__global__ __launch_bounds__(256) void mfma_gemm_alpha(
    const f16* __restrict__ A, const f16* __restrict__ Bt,
    f16* __restrict__ Tout,
    const float* __restrict__ avec_src, const float* __restrict__ avec_dst,
    float* __restrict__ asrc, float* __restrict__ adst,
    int M, int K, int Ncol) {
  constexpr int CF = BN / 16;
  constexpr int HL = BN / 64;
  __shared__ f16 As[128][40];
  __shared__ f16 Bs[BN][40];
  int tid = threadIdx.x;
  int wv = tid >> 6, lane = tid & 63;
  int lrow = lane & 15, lkb = lane >> 4;
  int row0 = blockIdx.x * 128, col0 = blockIdx.y * BN;

  f32x4 acc[2][CF];
#pragma unroll
  for (int rf = 0; rf < 2; ++rf)
#pragma unroll
    for (int cf = 0; cf < CF; ++cf) acc[rf][cf] = (f32x4){0.f, 0.f, 0.f, 0.f};

  for (int kk = 0; kk < K; kk += 32) {
#pragma unroll
    for (int q = 0; q < 2; ++q) {
      int slot = tid + q * 256;
      int r = slot >> 2, ko = (slot & 3) << 3;
      int gr = min(row0 + r, M - 1);
      *reinterpret_cast<f16x8*>(&As[r][ko]) =
          *reinterpret_cast<const f16x8*>(&A[(size_t)gr * K + kk + ko]);
    }
#pragma unroll
    for (int q = 0; q < BN / 64; ++q) {
      int slot = tid + q * 256;
      int c = slot >> 2, ko = (slot & 3) << 3;
      *reinterpret_cast<f16x8*>(&Bs[c][ko]) =
          *reinterpret_cast<const f16x8*>(&Bt[(size_t)(col0 + c) * K + kk + ko]);
    }
    __syncthreads();
    f16x8 af[2], bf[CF];
#pragma unroll
    for (int rf = 0; rf < 2; ++rf)
      af[rf] = *reinterpret_cast<f16x8*>(&As[wv * 32 + rf * 16 + lrow][lkb * 8]);
#pragma unroll
    for (int cf = 0; cf < CF; ++cf)
      bf[cf] = *reinterpret_cast<f16x8*>(&Bs[cf * 16 + lrow][lkb * 8]);
#pragma unroll
    for (int rf = 0; rf < 2; ++rf)
#pragma unroll
      for (int cf = 0; cf < CF; ++cf)
        acc[rf][cf] = __builtin_amdgcn_mfma_f32_16x16x32_f16(af[rf], bf[cf],
                                                             acc[rf][cf], 0, 0, 0);
    __syncthreads();
  }

  int Hh = Ncol >> 6;
  float avs[HL][4], avd[HL][4];
#pragma unroll
  for (int hl = 0; hl < HL; ++hl) {
    int hg = (col0 >> 6) + hl;
#pragma unroll
    for (int q = 0; q < 4; ++q) {
      avs[hl][q] = avec_src[hg * 64 + q * 16 + lrow];
      avd[hl][q] = avec_dst[hg * 64 + q * 16 + lrow];
    }
  }

#pragma unroll
  for (int rf = 0; rf < 2; ++rf) {
#pragma unroll
    for (int hl = 0; hl < HL; ++hl) {
      int hg = (col0 >> 6) + hl;
#pragma unroll
      for (int r = 0; r < 4; ++r) {
        float ps = 0.f, pd = 0.f;
#pragma unroll
        for (int q = 0; q < 4; ++q) {
          float v = acc[rf][hl * 4 + q][r];
          ps = fmaf(v, avs[hl][q], ps);
          pd = fmaf(v, avd[hl][q], pd);
        }
#pragma unroll
        for (int off = 1; off < 16; off <<= 1) {
          ps += __shfl_xor(ps, off);
          pd += __shfl_xor(pd, off);
        }
        int row = row0 + wv * 32 + rf * 16 + lkb * 4 + r;
        if (lrow == 0 && row < M) {
          asrc[row * Hh + hg] = ps;
          adst[row * Hh + hg] = pd;
        }
      }
    }
#pragma unroll
    for (int r = 0; r < 4; ++r) {
      int row = row0 + wv * 32 + rf * 16 + lkb * 4 + r;
      if (row < M) {
#pragma unroll
        for (int cf = 0; cf < CF; ++cf)
          Tout[(size_t)row * Ncol + col0 + cf * 16 + lrow] = (f16)acc[rf][cf][r];
      }
    }
  }
}

// Edge weights, layout [ET][4]: thread per (slot, head).
__global__ __launch_bounds__(256) void edge_weights_h4(
    const int* __restrict__ esrc, const int* __restrict__ edst,
    const float* __restrict__ asrc, const float* __restrict__ adst,
    float* __restrict__ w, int ET) {
  int t = blockIdx.x * 256 + threadIdx.x;
  if (t >= ET * 4) return;
  int j = t >> 2, h = t & 3;
  float e = asrc[esrc[j] * 4 + h] + adst[edst[j] * 4 + h];
  e = fmaxf(e, 0.2f * e);
  w[t] = __expf(e);
}

__global__ __launch_bounds__(256) void edge_weights_h1(
    const int* __restrict__ esrc, const int* __restrict__ edst,
    const float* __restrict__ asrc, const float* __restrict__ adst,
    float* __restrict__ w, int ET) {
  int j = blockIdx.x * 256 + threadIdx.x;
  if (j >= ET) return;
  float e = asrc[esrc[j]] + adst[edst[j]];
  e = fmaxf(e, 0.2f * e);
  w[j] = __expf(e);
}

// H=4 aggregate: ONE wave per dst (4 waves/block). Batched 8-edge prefetch:
// lanes 0-7 load 8 edges' esrc; lane (head*16 + i<8) loads w for (edge i,
// its head); __shfl broadcasts -> 8 independent gathers in flight. Lane owns
// 4 channels (8B of the 512B row). No reductions: every lane sees all edges.
template <bool ELU>
__global__ __launch_bounds__(256) void aggregate_h4(
    const f16* __restrict__ T16, const int* __restrict__ row_off,
    const int* __restrict__ esrc, const float* __restrict__ w,
    const float* __restrict__ bias, f16* __restrict__ outF, int N) {
  int wv = threadIdx.x >> 6, lane = threadIdx.x & 63;
  int dst = blockIdx.x * 4 + wv;
  if (dst >= N) return;
  int head = lane >> 4;
  int hsel = lane & 48;  // head*16
  int r0 = row_off[dst], r1 = row_off[dst + 1];
  const char* tbase = reinterpret_cast<const char*>(T16);
  uint loff = (uint)lane * 8;
  float den = 0.f, ax = 0.f, ay = 0.f, az = 0.f, aw = 0.f;
  for (int base = r0; base < r1; base += 8) {
    int jb = base + (lane & 7);
    int sv = 0;
    float wl = 0.f;
    if (jb < r1) {
      sv = esrc[jb];
      wl = w[(jb << 2) + head];
    }
#pragma unroll
    for (int i = 0; i < 8; ++i) {
      int sj = __shfl(sv, i);
      float wj = __shfl(wl, hsel + i);
      den += wj;
      uint2 raw = *reinterpret_cast<const uint2*>(tbase + (((uint)sj << 9) + loff));
      __half2 p0 = *reinterpret_cast<__half2*>(&raw.x);
      __half2 p1 = *reinterpret_cast<__half2*>(&raw.y);
      float2 f0 = __half22float2(p0);
      float2 f1 = __half22float2(p1);
      ax = fmaf(wj, f0.x, ax);
      ay = fmaf(wj, f0.y, ay);
      az = fmaf(wj, f1.x, az);
      aw = fmaf(wj, f1.y, aw);
    }
  }
  float rd = 1.f / den;
  float4 bv = *reinterpret_cast<const float4*>(&bias[lane << 2]);
  float vx = ax * rd + bv.x, vy = ay * rd + bv.y;
  float vz = az * rd + bv.z, vw = aw * rd + bv.w;
  if (ELU) {
    vx = vx > 0.f ? vx : expm1f(vx);
    vy = vy > 0.f ? vy : expm1f(vy);
    vz = vz > 0.f ? vz : expm1f(vz);
    vw = vw > 0.f ? vw : expm1f(vw);
  }
  f16 o[4] = {(f16)vx, (f16)vy, (f16)vz, (f16)vw};
  *reinterpret_cast<uint2*>(&outF[(size_t)dst * 256 + (lane << 2)]) =
      *reinterpret_cast<uint2*>(o);
}

// H=1 aggregate (layer 3): 16-lane group per dst (4 dst/wave, 16 dst/block),
// same 8-edge batched prefetch within the group. fp32 out.
__global__ __launch_bounds__(256) void aggregate_h1(
    const f16* __restrict__ T16, const int* __restrict__ row_off,
    const int* __restrict__ esrc, const float* __restrict__ w,
    const float* __restrict__ bias, float* __restrict__ out, int N) {
  int wv = threadIdx.x >> 6, lane = threadIdx.x & 63;
  int grp = lane >> 4, l = lane & 15;
  int gsel = lane & 48;
  int dst = blockIdx.x * 16 + wv * 4 + grp;
  if (dst >= N) return;
  int r0 = row_off[dst], r1 = row_off[dst + 1];
  const char* tbase = reinterpret_cast<const char*>(T16);
  uint loff = (uint)l * 8;
  float den = 0.f, ax = 0.f, ay = 0.f, az = 0.f, aw = 0.f;
  for (int base = r0; base < r1; base += 8) {
    int jb = base + (l & 7);
    int sv = 0;
    float wl = 0.f;
    if (jb < r1) {
      sv = esrc[jb];
      wl = w[jb];
    }
#pragma unroll
    for (int i = 0; i < 8; ++i) {
      int sj = __shfl(sv, gsel + i);
      float wj = __shfl(wl, gsel + i);
      den += wj;
      uint2 raw = *reinterpret_cast<const uint2*>(tbase + (((uint)sj << 7) + loff));
      __half2 p0 = *reinterpret_cast<__half2*>(&raw.x);
      __half2 p1 = *reinterpret_cast<__half2*>(&raw.y);
      float2 f0 = __half22float2(p0);
      float2 f1 = __half22float2(p1);
      ax = fmaf(wj, f0.x, ax);
      ay = fmaf(wj, f0.y, ay);
      az = fmaf(wj, f1.x, az);
      aw = fmaf(wj, f1.y, aw);
    }
  }
  float rd = 1.f / den;
  float4 v;
  v.x = ax * rd + bias[l * 4 + 0];
  v.y = ay * rd + bias[l * 4 + 1];
  v.z = az * rd + bias[l * 4 + 2];
  v.w = aw * rd + bias[l * 4 + 3];
  *reinterpret_cast<float4*>(&out[(size_t)dst * 64 + l * 4]) = v;
}

extern "C" void kernel_launch(void* const* d_in, const int* in_sizes, int n_in,
                              void* d_out, int out_size, void* d_ws, size_t ws_size,
                              hipStream_t stream) {
  const float* x   = (const float*)d_in[0];
  const int*   ei  = (const int*)d_in[1];
  const float* W1  = (const float*)d_in[2];
  const float* as1 = (const float*)d_in[3];
  const float* ad1 = (const float*)d_in[4];
  const float* b1  = (const float*)d_in[5];
  const float* W2  = (const float*)d_in[6];
  const float* as2 = (const float*)d_in[7];
  const float* ad2 = (const float*)d_in[8];
  const float* b2  = (const float*)d_in[9];
  const float* W3  = (const float*)d_in[10];
  const float* as3 = (const float*)d_in[11];
  const float* ad3 = (const float*)d_in[12];
  const float* b3  = (const float*)d_in[13];
  float* out = (float*)d_out;

  const int Fin = 128, H = 4, C = 64, HC = H * C;  // 256
  const int N = in_sizes[0] / Fin;
  const int E = in_sizes[1] / 2;
  const int ET = E + N;
  const int NB = (N + 1023) / 1024;

  // workspace layout (~93 MB)
  f16* xh    = (f16*)d_ws;                       // [N,128]
  f16* T16   = xh + (size_t)N * Fin;             // [N,256]
  f16* F16   = T16 + (size_t)N * HC;             // [N,256]
  f16* T16L3 = F16 + (size_t)N * HC;             // [N,64]
  f16* Wt1   = T16L3 + (size_t)N * C;            // [256,128]
  f16* Wt2   = Wt1 + HC * Fin;                   // [256,256]
  f16* Wt3   = Wt2 + HC * HC;                    // [64,256]
  float* asrc = (float*)(Wt3 + C * HC);          // [N,H]
  float* adst = asrc + (size_t)N * H;            // [N,H]
  float* wbuf = adst + (size_t)N * H;            // [ET*4]
  int* deg     = (int*)(wbuf + (size_t)ET * 4);
  int* row_off = deg + N;
  int* cursor  = row_off + (N + 1);
  int* bsum    = cursor + N;
  int* bpre    = bsum + NB;
  int* esrc    = bpre + NB;                      // [ET]
  int* edst    = esrc + ET;                      // [ET]

  // ---- CSR by destination ----
  hipMemsetAsync(deg, 0, N * sizeof(int), stream);
  count_kernel<<<(ET + 255) / 256, 256, 0, stream>>>(ei, E, N, deg);
  deg_block_reduce<<<NB, 256, 0, stream>>>(deg, bsum, N);
  small_scan<<<1, 1024, 0, stream>>>(bsum, bpre, NB);
  scan_final<<<NB, 1024, 0, stream>>>(deg, bpre, row_off, cursor, N, ET);
  scatter_kernel<<<(ET + 255) / 256, 256, 0, stream>>>(ei, E, N, cursor, esrc, edst);

  // ---- fp16 conversions ----
  convert_x<<<(N * Fin / 4 + 255) / 256, 256, 0, stream>>>(x, xh, N * Fin);
  convert_wt<<<(Fin * HC + 255) / 256, 256, 0, stream>>>(W1, Wt1, Fin, HC);
  convert_wt<<<(HC * HC + 255) / 256, 256, 0, stream>>>(W2, Wt2, HC, HC);
  convert_wt<<<(HC * C + 255) / 256, 256, 0, stream>>>(W3, Wt3, HC, C);

  int gx = (N + 127) / 128;
  int eb4 = (ET * 4 + 255) / 256, eb1 = (ET + 255) / 256;
  int ab4 = (N + 3) / 4;
  int ab1 = (N + 15) / 16;

  // ---- Layer 1: 128 -> 4x64 (concat) + ELU ----
  mfma_gemm_alpha<128><<<dim3(gx, 2), 256, 0, stream>>>(
      xh, Wt1, T16, as1, ad1, asrc, adst, N, Fin, HC);
  edge_weights_h4<<<eb4, 256, 0, stream>>>(esrc, edst, asrc, adst, wbuf, ET);
  aggregate_h4<true><<<ab4, 256, 0, stream>>>(T16, row_off, esrc, wbuf, b1, F16, N);

  // ---- Layer 2: 256 -> 4x64 (concat) + ELU ----
  mfma_gemm_alpha<128><<<dim3(gx, 2), 256, 0, stream>>>(
      F16, Wt2, T16, as2, ad2, asrc, adst, N, HC, HC);
  edge_weights_h4<<<eb4, 256, 0, stream>>>(esrc, edst, asrc, adst, wbuf, ET);
  aggregate_h4<true><<<ab4, 256, 0, stream>>>(T16, row_off, esrc, wbuf, b2, F16, N);

  // ---- Layer 3: 256 -> 1x64 ----
  mfma_gemm_alpha<64><<<dim3(gx, 1), 256, 0, stream>>>(
      F16, Wt3, T16L3, as3, ad3, asrc, adst, N, HC, C);
  edge_weights_h1<<<eb1, 256, 0, stream>>>(esrc, edst, asrc, adst, wbuf, ET);
  aggregate_h1<<<ab1, 256, 0, stream>>>(T16L3, row_off, esrc, wbuf, b3, out, N);
}